// Round 18
// baseline (431.233 us; speedup 1.0000x reference)
//
#include <hip/hip_runtime.h>

// GCN 4-layer: 29->96->128->64->32, N=50000, E=800000 (+self loops).
// Round 18 = round 15 (222.3 us, best) + agg_pre fused with the dense GEMM:
// one block = 32 nodes; aggregate x-hat into LDS (stride-40 rows, <=2-way
// banks), then GEMM 29->96 (relu*dis) -> LDS -> 96->32 in-block. Saves a
// dispatch + 12.8 MB Bb round-trip. __launch_bounds__(256,4) caps VGPR at
// 128 (no round-5/8 spill path). Weight collapse moved one hop earlier:
// W34+v1 rides place_x, W234+v2 rides prep_all.
// Build = round-15 place_x (XCD-affine sweep; two-phase bin/build of r16/17
// measured no better). 7 dispatches. No cooperative launches.
// NOTE: harness delivers integer inputs as int32.

constexpr int NN  = 50000;
constexpr int CAP = 64;    // max in-degree; Poisson(16) over 50K => P(>=64) ~ 0
constexpr int AGB = (NN * 8 + 255) / 256;          // width-32 agg blocks (1563)
constexpr int AGB32 = (NN + 31) / 32;              // agg+gemm blocks (1563)
constexpr int C1B = (NN + 255) / 256;              // width-1 agg blocks (196)
constexpr int PREPB = (NN * 32 + 64 + 255) / 256;  // prep_all main blocks
constexpr int W34XB = 17;                          // extra blocks: W34 (4096) + v1 (32)
constexpr int W234XB = 13;                         // extra blocks: W234 (3072) + v2 (32)
constexpr int PGB = 128;                           // place_x blocks per XCD group
constexpr int SLICE = (800000 + PGB - 1) / PGB;    // 6250 edges per block

typedef unsigned short u16;

// XCD-affine ELL build (round 15) + extra blocks: W34 = W3@W4, v1 = b3@W4.
__global__ void place_x_kernel(const int* __restrict__ row, const int* __restrict__ col,
                               int* __restrict__ cnt, u16* __restrict__ ell, int E,
                               const float* __restrict__ W3, const float* __restrict__ W4,
                               const float* __restrict__ b3,
                               float* __restrict__ W34, float* __restrict__ v1) {
    if (blockIdx.x >= 8 * PGB) {
        const int wid = (blockIdx.x - 8 * PGB) * 256 + threadIdx.x;
        if (wid < 4096) {                       // W34[r][j], lanes share r -> W3 scalarizes
            const int r = wid >> 5, j = wid & 31;
            float a = 0.f;
#pragma unroll 8
            for (int k = 0; k < 64; ++k) a = fmaf(W3[r * 64 + k], W4[k * 32 + j], a);
            W34[wid] = a;
        } else if (wid < 4128) {
            const int j = wid - 4096;
            float a = 0.f;
#pragma unroll 8
            for (int k = 0; k < 64; ++k) a = fmaf(b3[k], W4[k * 32 + j], a);
            v1[j] = a;
        }
        return;
    }
    const int g  = blockIdx.x & 7;
    const int bi = blockIdx.x >> 3;
    const int e0 = bi * SLICE;
    int e1 = e0 + SLICE; if (e1 > E) e1 = E;
    for (int e = e0 + threadIdx.x; e < e1; e += 256) {
        const int c = col[e];
        if ((unsigned)c >= (unsigned)NN || ((c >> 6) & 7) != g) continue;
        const int r = row[e];
        if ((unsigned)r >= (unsigned)NN) continue;
        const int pos = atomicAdd(&cnt[c], 1);
        if (pos < CAP) ell[c * CAP + pos] = (u16)r;
    }
}

// Main blocks: dis, ELL pad-to-8 with sentinel, x pad+prescale, zero rows.
// Extra blocks: W234 = W2@W34, v2 = b2@W34.
__global__ void prep_all_kernel(const int* __restrict__ cnt, u16* __restrict__ ell,
                                const float* __restrict__ x, float* __restrict__ dis,
                                float* __restrict__ Ba, float* __restrict__ Bb,
                                float* __restrict__ c1d,
                                const float* __restrict__ W2, const float* __restrict__ b2,
                                const float* __restrict__ W34,
                                float* __restrict__ W234, float* __restrict__ v2) {
    if (blockIdx.x >= PREPB) {
        const int wid = (blockIdx.x - PREPB) * 256 + threadIdx.x;
        if (wid < 3072) {                       // W234[r][j], lanes share r
            const int r = wid >> 5, j = wid & 31;
            float a = 0.f;
#pragma unroll 8
            for (int k = 0; k < 128; ++k) a = fmaf(W2[r * 128 + k], W34[k * 32 + j], a);
            W234[wid] = a;
        } else if (wid < 3104) {
            const int j = wid - 3072;
            float a = 0.f;
#pragma unroll 8
            for (int k = 0; k < 128; ++k) a = fmaf(b2[k], W34[k * 32 + j], a);
            v2[j] = a;
        }
        return;
    }
    const int idx = blockIdx.x * blockDim.x + threadIdx.x;
    if (idx < NN * 32) {
        const int n = idx >> 5, f = idx & 31;
        int m = cnt[n]; if (m > CAP) m = CAP;
        const float d = rsqrtf((float)m + 1.0f);     // +1 = self loop
        Ba[idx] = (f < 29) ? x[n * 29 + f] * d : 0.f;
        if (f == 31) dis[n] = d;
        if (f == 30) {                               // pad list to multiple of 8
            int mp = (m + 7) & ~7; if (mp > CAP) mp = CAP;
            for (int k = m; k < mp; ++k) ell[n * CAP + k] = (u16)NN;
        }
    } else {
        const int i = idx - NN * 32;
        if (i < 32) { Ba[NN * 32 + i] = 0.f; Bb[NN * 32 + i] = 0.f; }
        else if (i == 32) dis[NN] = 0.f;
        else if (i == 33) c1d[NN] = 0.f;
    }
}

// Width-32 pull body over u16 ELL: one int4 load = 8 indices = 8 gathers in
// flight. MODE: 0 out=dis*acc ; 1 chain out=dis^2*acc ; 2 final + fixups.
template<int MODE>
__device__ __forceinline__ void agg32_body(const float* __restrict__ hs,
                                           const int* __restrict__ cnt,
                                           const u16* __restrict__ ell,
                                           const float* __restrict__ dis,
                                           const float* __restrict__ c1,
                                           const float* __restrict__ c2,
                                           const float* __restrict__ v1,
                                           const float* __restrict__ v2,
                                           const float* __restrict__ bv,
                                           float* __restrict__ out) {
    const int idx = blockIdx.x * blockDim.x + threadIdx.x;
    if (idx >= NN * 8) return;
    const int n = idx >> 3, c = idx & 7;
    const float4* hpc = (const float4*)hs + c;
    float4 acc = hpc[n * 8];                    // self-loop term
    int m = cnt[n]; if (m > CAP) m = CAP;
    const int m8 = (m + 7) >> 3;
    const int4* ip = (const int4*)(ell + (size_t)n * CAP);
    for (int t = 0; t < m8; ++t) {
        const int4 s = ip[t];                   // 8 u16 indices
        const unsigned ux = (unsigned)s.x, uy = (unsigned)s.y;
        const unsigned uz = (unsigned)s.z, uw = (unsigned)s.w;
        const float4 g0 = hpc[(ux & 0xFFFFu) * 8], g1 = hpc[(ux >> 16) * 8];
        const float4 g2 = hpc[(uy & 0xFFFFu) * 8], g3 = hpc[(uy >> 16) * 8];
        const float4 g4 = hpc[(uz & 0xFFFFu) * 8], g5 = hpc[(uz >> 16) * 8];
        const float4 g6 = hpc[(uw & 0xFFFFu) * 8], g7 = hpc[(uw >> 16) * 8];
        acc.x += ((g0.x + g1.x) + (g2.x + g3.x)) + ((g4.x + g5.x) + (g6.x + g7.x));
        acc.y += ((g0.y + g1.y) + (g2.y + g3.y)) + ((g4.y + g5.y) + (g6.y + g7.y));
        acc.z += ((g0.z + g1.z) + (g2.z + g3.z)) + ((g4.z + g5.z) + (g6.z + g7.z));
        acc.w += ((g0.w + g1.w) + (g2.w + g3.w)) + ((g4.w + g5.w) + (g6.w + g7.w));
    }
    const float d = dis[n];
    float4 r;
    if (MODE == 0) {
        r.x = acc.x * d; r.y = acc.y * d; r.z = acc.z * d; r.w = acc.w * d;
    } else if (MODE == 1) {
        const float d2 = d * d;
        r.x = acc.x * d2; r.y = acc.y * d2; r.z = acc.z * d2; r.w = acc.w * d2;
    } else {
        const float a1 = c1[n], a2 = c2[n];
        const float4 w1 = ((const float4*)v1)[c];
        const float4 w2 = ((const float4*)v2)[c];
        const float4 bb = ((const float4*)bv)[c];
        r.x = fmaf(acc.x, d, fmaf(a1, w1.x, fmaf(a2, w2.x, bb.x)));
        r.y = fmaf(acc.y, d, fmaf(a1, w1.y, fmaf(a2, w2.y, bb.y)));
        r.z = fmaf(acc.z, d, fmaf(a1, w1.z, fmaf(a2, w2.z, bb.z)));
        r.w = fmaf(acc.w, d, fmaf(a1, w1.w, fmaf(a2, w2.w, bb.w)));
    }
    ((float4*)out)[idx] = r;
}

// Width-1 pull: out[n] = dis[n]*(in[n] + sum in[src]); optional outd = out*dis.
__device__ __forceinline__ void agg1_body(const float* __restrict__ in,
                                          const int* __restrict__ cnt,
                                          const u16* __restrict__ ell,
                                          const float* __restrict__ dis,
                                          float* __restrict__ out,
                                          float* __restrict__ outd, int blk0) {
    const int n = (blockIdx.x - blk0) * 256 + threadIdx.x;
    if (n >= NN) return;
    float acc = in[n];
    int m = cnt[n]; if (m > CAP) m = CAP;
    const int m8 = (m + 7) >> 3;
    const int4* ip = (const int4*)(ell + (size_t)n * CAP);
    for (int t = 0; t < m8; ++t) {
        const int4 s = ip[t];
        const unsigned ux = (unsigned)s.x, uy = (unsigned)s.y;
        const unsigned uz = (unsigned)s.z, uw = (unsigned)s.w;
        acc += ((in[ux & 0xFFFFu] + in[ux >> 16]) + (in[uy & 0xFFFFu] + in[uy >> 16]))
             + ((in[uz & 0xFFFFu] + in[uz >> 16]) + (in[uw & 0xFFFFu] + in[uw >> 16]));
    }
    const float r = dis[n] * acc;
    out[n] = r;
    if (outd) outd[n] = r * dis[n];
}

// Fused: layer-1 pre-agg (32 nodes/block, into LDS) + GEMM 29->96 relu*dis
// (LDS) + GEMM 96->32 -> G. Extra blocks (>= AGB32): c1 = A.1 fold.
__global__ void __launch_bounds__(256, 4)
agg_gemm_kernel(const float* __restrict__ Ba, const int* __restrict__ cnt,
                const u16* __restrict__ ell, const float* __restrict__ dis,
                const float* __restrict__ W1, const float* __restrict__ b1,
                const float* __restrict__ W234, float* __restrict__ G,
                float* __restrict__ c1, float* __restrict__ c1d) {
    if (blockIdx.x >= AGB32) {                  // folded c1 = A.1 (uniform per block)
        agg1_body(dis, cnt, ell, dis, c1, c1d, AGB32);
        return;
    }
    constexpr int RSX = 40, RSH = 104;
    __shared__ float xs[32 * RSX];
    __shared__ float hsm[32 * RSH];
    const int t = threadIdx.x;
    const int nl = t >> 3, c = t & 7;
    const int n = blockIdx.x * 32 + nl;

    // --- aggregation: x-hat row chunk -> LDS ---
    float4 r = make_float4(0.f, 0.f, 0.f, 0.f);
    if (n < NN) {
        const float4* hpc = (const float4*)Ba + c;
        float4 acc = hpc[n * 8];                // self-loop term
        int m = cnt[n]; if (m > CAP) m = CAP;
        const int m8 = (m + 7) >> 3;
        const int4* ip = (const int4*)(ell + (size_t)n * CAP);
        for (int tt = 0; tt < m8; ++tt) {
            const int4 s = ip[tt];
            const unsigned ux = (unsigned)s.x, uy = (unsigned)s.y;
            const unsigned uz = (unsigned)s.z, uw = (unsigned)s.w;
            const float4 g0 = hpc[(ux & 0xFFFFu) * 8], g1 = hpc[(ux >> 16) * 8];
            const float4 g2 = hpc[(uy & 0xFFFFu) * 8], g3 = hpc[(uy >> 16) * 8];
            const float4 g4 = hpc[(uz & 0xFFFFu) * 8], g5 = hpc[(uz >> 16) * 8];
            const float4 g6 = hpc[(uw & 0xFFFFu) * 8], g7 = hpc[(uw >> 16) * 8];
            acc.x += ((g0.x + g1.x) + (g2.x + g3.x)) + ((g4.x + g5.x) + (g6.x + g7.x));
            acc.y += ((g0.y + g1.y) + (g2.y + g3.y)) + ((g4.y + g5.y) + (g6.y + g7.y));
            acc.z += ((g0.z + g1.z) + (g2.z + g3.z)) + ((g4.z + g5.z) + (g6.z + g7.z));
            acc.w += ((g0.w + g1.w) + (g2.w + g3.w)) + ((g4.w + g5.w) + (g6.w + g7.w));
        }
        const float d = dis[n];
        r.x = acc.x * d; r.y = acc.y * d; r.z = acc.z * d; r.w = acc.w * d;
    }
    *(float4*)(xs + nl * RSX + c * 4) = r;
    __syncthreads();

    // --- phase A: 29 -> 96, relu(+b1)*dis; thread = (node nl, 12 cols) ---
    {
        const float* xr = xs + nl * RSX;
        const float4* Wv = (const float4*)W1;       // 24 float4 per k-row
        float4 a0 = make_float4(0.f, 0.f, 0.f, 0.f);
        float4 a1 = make_float4(0.f, 0.f, 0.f, 0.f);
        float4 a2 = make_float4(0.f, 0.f, 0.f, 0.f);
#pragma unroll
        for (int k = 0; k < 29; ++k) {
            const float xv = xr[k];                 // broadcast across c-lanes
            const float4 w0 = Wv[k * 24 + c * 3 + 0];
            const float4 w1w = Wv[k * 24 + c * 3 + 1];
            const float4 w2w = Wv[k * 24 + c * 3 + 2];
            a0.x = fmaf(xv, w0.x, a0.x); a0.y = fmaf(xv, w0.y, a0.y);
            a0.z = fmaf(xv, w0.z, a0.z); a0.w = fmaf(xv, w0.w, a0.w);
            a1.x = fmaf(xv, w1w.x, a1.x); a1.y = fmaf(xv, w1w.y, a1.y);
            a1.z = fmaf(xv, w1w.z, a1.z); a1.w = fmaf(xv, w1w.w, a1.w);
            a2.x = fmaf(xv, w2w.x, a2.x); a2.y = fmaf(xv, w2w.y, a2.y);
            a2.z = fmaf(xv, w2w.z, a2.z); a2.w = fmaf(xv, w2w.w, a2.w);
        }
        const float d = (n < NN) ? dis[n] : 0.f;
#pragma unroll
        for (int j = 0; j < 3; ++j) {
            const float4 a = (j == 0) ? a0 : (j == 1) ? a1 : a2;
            const float4 bb = ((const float4*)b1)[c * 3 + j];
            float4 h;
            h.x = fmaxf(a.x + bb.x, 0.f) * d; h.y = fmaxf(a.y + bb.y, 0.f) * d;
            h.z = fmaxf(a.z + bb.z, 0.f) * d; h.w = fmaxf(a.w + bb.w, 0.f) * d;
            *(float4*)(hsm + nl * RSH + (c * 3 + j) * 4) = h;
        }
    }
    __syncthreads();

    // --- phase B: 96 -> 32 raw; thread = (node nl, 4 cols) ---
    {
        const float* hr = hsm + nl * RSH;
        const float4* Wv = (const float4*)W234;     // 8 float4 per k-row
        float4 a = make_float4(0.f, 0.f, 0.f, 0.f);
#pragma unroll 8
        for (int k = 0; k < 96; ++k) {
            const float4 w = Wv[k * 8 + c];
            const float v = hr[k];
            a.x = fmaf(v, w.x, a.x); a.y = fmaf(v, w.y, a.y);
            a.z = fmaf(v, w.z, a.z); a.w = fmaf(v, w.w, a.w);
        }
        if (n < NN) ((float4*)(G + (size_t)n * 32))[c] = a;
    }
}

// Hop 1 (mode 1) + folded c2 = A.(c1*dis).
__global__ void agg_hop1_kernel(const float* __restrict__ Ba, const int* __restrict__ cnt,
                                const u16* __restrict__ ell, const float* __restrict__ dis,
                                float* __restrict__ Bb, const float* __restrict__ c1d,
                                float* __restrict__ c2) {
    if (blockIdx.x < AGB)
        agg32_body<1>(Ba, cnt, ell, dis, nullptr, nullptr, nullptr, nullptr, nullptr, Bb);
    else
        agg1_body(c1d, cnt, ell, dis, c2, nullptr, AGB);
}

// Hop 2 (mode 1).
__global__ void agg_hop2_kernel(const float* __restrict__ Bb, const int* __restrict__ cnt,
                                const u16* __restrict__ ell, const float* __restrict__ dis,
                                float* __restrict__ Ba) {
    agg32_body<1>(Bb, cnt, ell, dis, nullptr, nullptr, nullptr, nullptr, nullptr, Ba);
}

// Hop 3 + rank-1 fixups (mode 2).
__global__ void agg_hop3_kernel(const float* __restrict__ Ba, const int* __restrict__ cnt,
                                const u16* __restrict__ ell, const float* __restrict__ dis,
                                const float* __restrict__ c1, const float* __restrict__ c2,
                                const float* __restrict__ v1, const float* __restrict__ v2,
                                const float* __restrict__ bv, float* __restrict__ out) {
    agg32_body<2>(Ba, cnt, ell, dis, c1, c2, v1, v2, bv, out);
}

extern "C" void kernel_launch(void* const* d_in, const int* in_sizes, int n_in,
                              void* d_out, int out_size, void* d_ws, size_t ws_size,
                              hipStream_t stream) {
    const float* x  = (const float*)d_in[0];
    const int*   ei = (const int*)d_in[1];           // int32 (harness converts)
    const float* W1 = (const float*)d_in[2]; const float* b1 = (const float*)d_in[3];
    const float* W2 = (const float*)d_in[4]; const float* b2 = (const float*)d_in[5];
    const float* W3 = (const float*)d_in[6]; const float* b3 = (const float*)d_in[7];
    const float* W4 = (const float*)d_in[8]; const float* b4p = (const float*)d_in[9];
    float* outp = (float*)d_out;

    const int E = in_sizes[1] / 2;          // 800000
    const int* row = ei;
    const int* col = ei + E;

    // Workspace (4B elems, 16B-aligned sections), ~20 MB:
    int*   cnt  = (int*)d_ws;                       // 50048 ints
    float* dis  = (float*)(cnt + 50048);            // 50056 floats (uses [NN])
    u16*   ell  = (u16*)(dis + 50056);              // NN*CAP u16 = 1,600,000 ints
    float* c1   = (float*)((int*)ell + 1600000);    // 50056
    float* c1d  = c1 + 50056;                       // 50056 (uses [NN])
    float* c2   = c1d + 50056;                      // 50056
    float* W34  = c2 + 50056;                       // 4096
    float* W234 = W34 + 4096;                       // 3072
    float* v1   = W234 + 3072;                      // 32
    float* v2   = v1 + 32;                          // 32
    float* Ba   = v2 + 32;                          // (NN+1)*32
    float* Bb   = Ba + 1600064;                     // (NN+1)*32

    // 1. zero counters
    hipMemsetAsync(cnt, 0, 50048 * sizeof(int), stream);
    // 2. build ELL, XCD-affine; extra blocks: W34 + v1
    place_x_kernel<<<8 * PGB + W34XB, 256, 0, stream>>>(row, col, cnt, ell, E,
                                                        W3, W4, b3, W34, v1);
    // 3. dis + pad + xpad + sentinels; extra blocks: W234 + v2
    prep_all_kernel<<<PREPB + W234XB, 256, 0, stream>>>(cnt, ell, x, dis, Ba, Bb, c1d,
                                                        W2, b2, W34, W234, v2);
    // 4. fused pre-agg + dense GEMMs (Ba -> Bb) + folded c1
    agg_gemm_kernel<<<AGB32 + C1B, 256, 0, stream>>>(Ba, cnt, ell, dis,
                                                     W1, b1, W234, Bb, c1, c1d);
    // 5. hop 1 (Bb->Ba) + folded c2
    agg_hop1_kernel<<<AGB + C1B, 256, 0, stream>>>(Bb, cnt, ell, dis, Ba, c1d, c2);
    // 6. hop 2 (Ba->Bb)
    agg_hop2_kernel<<<AGB, 256, 0, stream>>>(Ba, cnt, ell, dis, Bb);
    // 7. hop 3 + rank-1 fixups (Bb->out)
    agg_hop3_kernel<<<AGB, 256, 0, stream>>>(Bb, cnt, ell, dis, c1, c2, v1, v2, b4p, outp);
}

// Round 19
// 221.874 us; speedup vs baseline: 1.9436x; 1.9436x over previous
//
#include <hip/hip_runtime.h>

// GCN 4-layer: 29->96->128->64->32, N=50000, E=800000 (+self loops).
// Round 19 = round 15 (222.3 us, best) + hop gathers unrolled x2 (16 loads
// in flight; hops are latency-bound at VALUBusy<7%). Round-18's fused
// agg+GEMM spilled (3rd spill: >8 accs/thread always spills on this
// compiler) - dense path stays as r15's gemm_fused(192,2) with 8 accs.
// Structure: collapsed layers 2-4 (out = A^3(h1 W234)+c2 v2+c1 v1+b4),
// u16 ELL + 8-index int4 gathers, XCD-affine build, weight collapse riding
// prep/agg_pre. 8 dispatches. No cooperative launches.
// NOTE: harness delivers integer inputs as int32.

constexpr int NN  = 50000;
constexpr int CAP = 64;    // max in-degree; Poisson(16) over 50K => P(>=64) ~ 0
constexpr int AGB = (NN * 8 + 255) / 256;          // width-32 agg blocks (1563)
constexpr int C1B = (NN + 255) / 256;              // width-1 agg blocks (196)
constexpr int PREPB = (NN * 32 + 64 + 255) / 256;  // prep_all main blocks
constexpr int W34XB = 17;                          // extra blocks: w34 (4096) + v1 (32)
constexpr int W234XB = 13;                         // extra blocks: W234 (3072) + v2 (32)
constexpr int PGB = 128;                           // blocks per XCD group
constexpr int SLICE = (800000 + PGB - 1) / PGB;    // 6250 edges per block

typedef unsigned short u16;

// XCD-affine ELL build: 8 groups x 128 blocks; group g keeps dests with
// (c>>6)&7 == g -> ELL/cnt lines single-XCD-written.
__global__ void place_x_kernel(const int* __restrict__ row, const int* __restrict__ col,
                               int* __restrict__ cnt, u16* __restrict__ ell, int E) {
    const int g  = blockIdx.x & 7;
    const int bi = blockIdx.x >> 3;
    const int e0 = bi * SLICE;
    int e1 = e0 + SLICE; if (e1 > E) e1 = E;
    for (int e = e0 + threadIdx.x; e < e1; e += 256) {
        const int c = col[e];
        if ((unsigned)c >= (unsigned)NN || ((c >> 6) & 7) != g) continue;
        const int r = row[e];
        if ((unsigned)r >= (unsigned)NN) continue;
        const int pos = atomicAdd(&cnt[c], 1);
        if (pos < CAP) ell[c * CAP + pos] = (u16)r;
    }
}

// Main blocks: dis, ELL pad-to-8 with sentinel, x pad+prescale, zero rows.
// Extra blocks (>= PREPB): W34 = W3@W4 + v1 = b3@W4.
__global__ void prep_all_kernel(const int* __restrict__ cnt, u16* __restrict__ ell,
                                const float* __restrict__ x, float* __restrict__ dis,
                                float* __restrict__ Ba, float* __restrict__ Bb,
                                float* __restrict__ c1d,
                                const float* __restrict__ W3, const float* __restrict__ W4,
                                const float* __restrict__ b3,
                                float* __restrict__ W34, float* __restrict__ v1) {
    if (blockIdx.x >= PREPB) {
        const int wid = (blockIdx.x - PREPB) * 256 + threadIdx.x;
        if (wid < 4096) {                       // W34[r][j], lanes share r -> W3 scalarizes
            const int r = wid >> 5, j = wid & 31;
            float a = 0.f;
#pragma unroll 8
            for (int k = 0; k < 64; ++k) a = fmaf(W3[r * 64 + k], W4[k * 32 + j], a);
            W34[wid] = a;
        } else if (wid < 4128) {
            const int j = wid - 4096;
            float a = 0.f;
#pragma unroll 8
            for (int k = 0; k < 64; ++k) a = fmaf(b3[k], W4[k * 32 + j], a);
            v1[j] = a;
        }
        return;
    }
    const int idx = blockIdx.x * blockDim.x + threadIdx.x;
    if (idx < NN * 32) {
        const int n = idx >> 5, f = idx & 31;
        int m = cnt[n]; if (m > CAP) m = CAP;
        const float d = rsqrtf((float)m + 1.0f);     // +1 = self loop
        Ba[idx] = (f < 29) ? x[n * 29 + f] * d : 0.f;
        if (f == 31) dis[n] = d;
        if (f == 30) {                               // pad list to multiple of 8
            int mp = (m + 7) & ~7; if (mp > CAP) mp = CAP;
            for (int k = m; k < mp; ++k) ell[n * CAP + k] = (u16)NN;
        }
    } else {
        const int i = idx - NN * 32;
        if (i < 32) { Ba[NN * 32 + i] = 0.f; Bb[NN * 32 + i] = 0.f; }
        else if (i == 32) dis[NN] = 0.f;
        else if (i == 33) c1d[NN] = 0.f;
    }
}

// Width-32 pull body, u16 ELL, index loads unrolled x2 -> 16 gathers in
// flight. MODE: 0 out=dis*acc ; 1 chain out=dis^2*acc ; 2 final + fixups.
template<int MODE>
__device__ __forceinline__ void agg32_body(const float* __restrict__ hs,
                                           const int* __restrict__ cnt,
                                           const u16* __restrict__ ell,
                                           const float* __restrict__ dis,
                                           const float* __restrict__ c1,
                                           const float* __restrict__ c2,
                                           const float* __restrict__ v1,
                                           const float* __restrict__ v2,
                                           const float* __restrict__ bv,
                                           float* __restrict__ out) {
    const int idx = blockIdx.x * blockDim.x + threadIdx.x;
    if (idx >= NN * 8) return;
    const int n = idx >> 3, c = idx & 7;
    const float4* hpc = (const float4*)hs + c;
    float4 acc = hpc[n * 8];                    // self-loop term
    int m = cnt[n]; if (m > CAP) m = CAP;
    const int m8 = (m + 7) >> 3;
    const int4* ip = (const int4*)(ell + (size_t)n * CAP);
    int t = 0;
    for (; t + 2 <= m8; t += 2) {               // 16 gathers in flight
        const int4 sA = ip[t], sB = ip[t + 1];
        const unsigned ax = (unsigned)sA.x, ay = (unsigned)sA.y;
        const unsigned az = (unsigned)sA.z, aw = (unsigned)sA.w;
        const unsigned bx = (unsigned)sB.x, by = (unsigned)sB.y;
        const unsigned bz = (unsigned)sB.z, bw = (unsigned)sB.w;
        const float4 g0 = hpc[(ax & 0xFFFFu) * 8], g1 = hpc[(ax >> 16) * 8];
        const float4 g2 = hpc[(ay & 0xFFFFu) * 8], g3 = hpc[(ay >> 16) * 8];
        const float4 g4 = hpc[(az & 0xFFFFu) * 8], g5 = hpc[(az >> 16) * 8];
        const float4 g6 = hpc[(aw & 0xFFFFu) * 8], g7 = hpc[(aw >> 16) * 8];
        const float4 h0 = hpc[(bx & 0xFFFFu) * 8], h1 = hpc[(bx >> 16) * 8];
        const float4 h2 = hpc[(by & 0xFFFFu) * 8], h3 = hpc[(by >> 16) * 8];
        const float4 h4 = hpc[(bz & 0xFFFFu) * 8], h5 = hpc[(bz >> 16) * 8];
        const float4 h6 = hpc[(bw & 0xFFFFu) * 8], h7 = hpc[(bw >> 16) * 8];
        acc.x += (((g0.x + g1.x) + (g2.x + g3.x)) + ((g4.x + g5.x) + (g6.x + g7.x)))
               + (((h0.x + h1.x) + (h2.x + h3.x)) + ((h4.x + h5.x) + (h6.x + h7.x)));
        acc.y += (((g0.y + g1.y) + (g2.y + g3.y)) + ((g4.y + g5.y) + (g6.y + g7.y)))
               + (((h0.y + h1.y) + (h2.y + h3.y)) + ((h4.y + h5.y) + (h6.y + h7.y)));
        acc.z += (((g0.z + g1.z) + (g2.z + g3.z)) + ((g4.z + g5.z) + (g6.z + g7.z)))
               + (((h0.z + h1.z) + (h2.z + h3.z)) + ((h4.z + h5.z) + (h6.z + h7.z)));
        acc.w += (((g0.w + g1.w) + (g2.w + g3.w)) + ((g4.w + g5.w) + (g6.w + g7.w)))
               + (((h0.w + h1.w) + (h2.w + h3.w)) + ((h4.w + h5.w) + (h6.w + h7.w)));
    }
    if (t < m8) {
        const int4 s = ip[t];
        const unsigned ux = (unsigned)s.x, uy = (unsigned)s.y;
        const unsigned uz = (unsigned)s.z, uw = (unsigned)s.w;
        const float4 g0 = hpc[(ux & 0xFFFFu) * 8], g1 = hpc[(ux >> 16) * 8];
        const float4 g2 = hpc[(uy & 0xFFFFu) * 8], g3 = hpc[(uy >> 16) * 8];
        const float4 g4 = hpc[(uz & 0xFFFFu) * 8], g5 = hpc[(uz >> 16) * 8];
        const float4 g6 = hpc[(uw & 0xFFFFu) * 8], g7 = hpc[(uw >> 16) * 8];
        acc.x += ((g0.x + g1.x) + (g2.x + g3.x)) + ((g4.x + g5.x) + (g6.x + g7.x));
        acc.y += ((g0.y + g1.y) + (g2.y + g3.y)) + ((g4.y + g5.y) + (g6.y + g7.y));
        acc.z += ((g0.z + g1.z) + (g2.z + g3.z)) + ((g4.z + g5.z) + (g6.z + g7.z));
        acc.w += ((g0.w + g1.w) + (g2.w + g3.w)) + ((g4.w + g5.w) + (g6.w + g7.w));
    }
    const float d = dis[n];
    float4 r;
    if (MODE == 0) {
        r.x = acc.x * d; r.y = acc.y * d; r.z = acc.z * d; r.w = acc.w * d;
    } else if (MODE == 1) {
        const float d2 = d * d;
        r.x = acc.x * d2; r.y = acc.y * d2; r.z = acc.z * d2; r.w = acc.w * d2;
    } else {
        const float a1 = c1[n], a2 = c2[n];
        const float4 w1 = ((const float4*)v1)[c];
        const float4 w2 = ((const float4*)v2)[c];
        const float4 bb = ((const float4*)bv)[c];
        r.x = fmaf(acc.x, d, fmaf(a1, w1.x, fmaf(a2, w2.x, bb.x)));
        r.y = fmaf(acc.y, d, fmaf(a1, w1.y, fmaf(a2, w2.y, bb.y)));
        r.z = fmaf(acc.z, d, fmaf(a1, w1.z, fmaf(a2, w2.z, bb.z)));
        r.w = fmaf(acc.w, d, fmaf(a1, w1.w, fmaf(a2, w2.w, bb.w)));
    }
    ((float4*)out)[idx] = r;
}

// Width-1 pull: out[n] = dis[n]*(in[n] + sum in[src]); optional outd = out*dis.
__device__ __forceinline__ void agg1_body(const float* __restrict__ in,
                                          const int* __restrict__ cnt,
                                          const u16* __restrict__ ell,
                                          const float* __restrict__ dis,
                                          float* __restrict__ out,
                                          float* __restrict__ outd, int blk0) {
    const int n = (blockIdx.x - blk0) * 256 + threadIdx.x;
    if (n >= NN) return;
    float acc = in[n];
    int m = cnt[n]; if (m > CAP) m = CAP;
    const int m8 = (m + 7) >> 3;
    const int4* ip = (const int4*)(ell + (size_t)n * CAP);
    for (int t = 0; t < m8; ++t) {
        const int4 s = ip[t];
        const unsigned ux = (unsigned)s.x, uy = (unsigned)s.y;
        const unsigned uz = (unsigned)s.z, uw = (unsigned)s.w;
        acc += ((in[ux & 0xFFFFu] + in[ux >> 16]) + (in[uy & 0xFFFFu] + in[uy >> 16]))
             + ((in[uz & 0xFFFFu] + in[uz >> 16]) + (in[uw & 0xFFFFu] + in[uw >> 16]));
    }
    const float r = dis[n] * acc;
    out[n] = r;
    if (outd) outd[n] = r * dis[n];
}

// Layer-1 pre-agg (mode 0) + folded c1 = A.1 + folded W234 = W2@W34, v2 = b2@W34.
__global__ void agg_pre_kernel(const float* __restrict__ Ba, const int* __restrict__ cnt,
                               const u16* __restrict__ ell, const float* __restrict__ dis,
                               float* __restrict__ Bb, float* __restrict__ c1,
                               float* __restrict__ c1d,
                               const float* __restrict__ W2, const float* __restrict__ b2,
                               const float* __restrict__ W34, float* __restrict__ W234,
                               float* __restrict__ v2) {
    if (blockIdx.x < AGB) {
        agg32_body<0>(Ba, cnt, ell, dis, nullptr, nullptr, nullptr, nullptr, nullptr, Bb);
    } else if (blockIdx.x < AGB + C1B) {
        agg1_body(dis, cnt, ell, dis, c1, c1d, AGB);
    } else {
        const int wid = (blockIdx.x - AGB - C1B) * 256 + threadIdx.x;
        if (wid < 3072) {                       // W234[r][j], lanes share r
            const int r = wid >> 5, j = wid & 31;
            float a = 0.f;
#pragma unroll 8
            for (int k = 0; k < 128; ++k) a = fmaf(W2[r * 128 + k], W34[k * 32 + j], a);
            W234[wid] = a;
        } else if (wid < 3104) {
            const int j = wid - 3072;
            float a = 0.f;
#pragma unroll 8
            for (int k = 0; k < 128; ++k) a = fmaf(b2[k], W34[k * 32 + j], a);
            v2[j] = a;
        }
    }
}

// Hop 1 (mode 1) + folded c2 = A.(c1*dis).
__global__ void agg_hop1_kernel(const float* __restrict__ Ba, const int* __restrict__ cnt,
                                const u16* __restrict__ ell, const float* __restrict__ dis,
                                float* __restrict__ Bb, const float* __restrict__ c1d,
                                float* __restrict__ c2) {
    if (blockIdx.x < AGB)
        agg32_body<1>(Ba, cnt, ell, dis, nullptr, nullptr, nullptr, nullptr, nullptr, Bb);
    else
        agg1_body(c1d, cnt, ell, dis, c2, nullptr, AGB);
}

// Hop 2 (mode 1).
__global__ void agg_hop2_kernel(const float* __restrict__ Bb, const int* __restrict__ cnt,
                                const u16* __restrict__ ell, const float* __restrict__ dis,
                                float* __restrict__ Ba) {
    agg32_body<1>(Bb, cnt, ell, dis, nullptr, nullptr, nullptr, nullptr, nullptr, Ba);
}

// Hop 3 + rank-1 fixups (mode 2).
__global__ void agg_hop3_kernel(const float* __restrict__ Ba, const int* __restrict__ cnt,
                                const u16* __restrict__ ell, const float* __restrict__ dis,
                                const float* __restrict__ c1, const float* __restrict__ c2,
                                const float* __restrict__ v1, const float* __restrict__ v2,
                                const float* __restrict__ bv, float* __restrict__ out) {
    agg32_body<2>(Ba, cnt, ell, dis, c1, c2, v1, v2, bv, out);
}

// Fused dense path: h1d = relu(Xa@W1+b1)*dis (LDS), g = h1d@W234 -> G.
// 8 accs/thread max; __launch_bounds__(192,2) -> no spill (r13-proven).
__global__ void __launch_bounds__(192, 2)
gemm_fused_kernel(const float* __restrict__ X, const float* __restrict__ W1,
                  const float* __restrict__ b1, const float* __restrict__ dis,
                  const float* __restrict__ W234, float* __restrict__ G) {
    constexpr int NPB = 16, RSX = 36, RSH = 104;
    __shared__ float xs[NPB * RSX];
    __shared__ float hsm[NPB * RSH];
    const int tid = threadIdx.x;
    const int n0  = blockIdx.x * NPB;

    const float4* Xv = (const float4*)(X + (size_t)n0 * 32);
    for (int i = tid; i < NPB * 8; i += 192) {
        const int nl = i >> 3, r = i & 7;
        float4 v = make_float4(0.f, 0.f, 0.f, 0.f);
        if (n0 + nl < NN) v = Xv[nl * 8 + r];
        *(float4*)(xs + nl * RSX + r * 4) = v;
    }
    __syncthreads();

    {   // phase A: 29 -> 96, relu(+b1)*dis, result to LDS
        const int cg = tid % 24, g = tid / 24;
        const float* x0 = xs + (2 * g) * RSX;
        const float* x1 = x0 + RSX;
        const float4* Wv = (const float4*)W1;
        float4 a0 = make_float4(0.f, 0.f, 0.f, 0.f);
        float4 a1 = make_float4(0.f, 0.f, 0.f, 0.f);
#pragma unroll
        for (int k = 0; k < 29; ++k) {
            const float4 w = Wv[k * 24 + cg];
            const float v0 = x0[k], v1 = x1[k];
            a0.x = fmaf(v0, w.x, a0.x); a0.y = fmaf(v0, w.y, a0.y);
            a0.z = fmaf(v0, w.z, a0.z); a0.w = fmaf(v0, w.w, a0.w);
            a1.x = fmaf(v1, w.x, a1.x); a1.y = fmaf(v1, w.y, a1.y);
            a1.z = fmaf(v1, w.z, a1.z); a1.w = fmaf(v1, w.w, a1.w);
        }
        const float4 bb = ((const float4*)b1)[cg];
#pragma unroll
        for (int h = 0; h < 2; ++h) {
            const int nl = 2 * g + h, node = n0 + nl;
            const float d = (node < NN) ? dis[node] : 0.f;
            const float4 a = h ? a1 : a0;
            float4 r;
            r.x = fmaxf(a.x + bb.x, 0.f) * d; r.y = fmaxf(a.y + bb.y, 0.f) * d;
            r.z = fmaxf(a.z + bb.z, 0.f) * d; r.w = fmaxf(a.w + bb.w, 0.f) * d;
            *(float4*)(hsm + nl * RSH + cg * 4) = r;
        }
    }
    __syncthreads();

    if (tid < 128) {  // phase B: 96 -> 32 raw
        const int nl = tid >> 3, cg = tid & 7;
        const float* hr = hsm + nl * RSH;
        const float4* Wv = (const float4*)W234;
        float4 a = make_float4(0.f, 0.f, 0.f, 0.f);
#pragma unroll 8
        for (int k = 0; k < 96; ++k) {
            const float4 w = Wv[k * 8 + cg];
            const float v = hr[k];
            a.x = fmaf(v, w.x, a.x); a.y = fmaf(v, w.y, a.y);
            a.z = fmaf(v, w.z, a.z); a.w = fmaf(v, w.w, a.w);
        }
        const int node = n0 + nl;
        if (node < NN) ((float4*)(G + (size_t)node * 32))[cg] = a;
    }
}

extern "C" void kernel_launch(void* const* d_in, const int* in_sizes, int n_in,
                              void* d_out, int out_size, void* d_ws, size_t ws_size,
                              hipStream_t stream) {
    const float* x  = (const float*)d_in[0];
    const int*   ei = (const int*)d_in[1];           // int32 (harness converts)
    const float* W1 = (const float*)d_in[2]; const float* b1 = (const float*)d_in[3];
    const float* W2 = (const float*)d_in[4]; const float* b2 = (const float*)d_in[5];
    const float* W3 = (const float*)d_in[6]; const float* b3 = (const float*)d_in[7];
    const float* W4 = (const float*)d_in[8]; const float* b4p = (const float*)d_in[9];
    float* outp = (float*)d_out;

    const int E = in_sizes[1] / 2;          // 800000
    const int* row = ei;
    const int* col = ei + E;

    // Workspace (4B elems, 16B-aligned sections), ~20 MB:
    int*   cnt  = (int*)d_ws;                       // 50048 ints
    float* dis  = (float*)(cnt + 50048);            // 50056 floats (uses [NN])
    u16*   ell  = (u16*)(dis + 50056);              // NN*CAP u16 = 1,600,000 ints
    float* c1   = (float*)((int*)ell + 1600000);    // 50056
    float* c1d  = c1 + 50056;                       // 50056 (uses [NN])
    float* c2   = c1d + 50056;                      // 50056
    float* W34  = c2 + 50056;                       // 4096
    float* W234 = W34 + 4096;                       // 3072
    float* v1   = W234 + 3072;                      // 32
    float* v2   = v1 + 32;                          // 32
    float* Ba   = v2 + 32;                          // (NN+1)*32
    float* Bb   = Ba + 1600064;                     // (NN+1)*32

    // 1. zero counters
    hipMemsetAsync(cnt, 0, 50048 * sizeof(int), stream);
    // 2. build ELL, XCD-affine (8 groups x 128 blocks)
    place_x_kernel<<<8 * PGB, 256, 0, stream>>>(row, col, cnt, ell, E);
    // 3. dis + pad + xpad + sentinels; extra blocks: W34 + v1
    prep_all_kernel<<<PREPB + W34XB, 256, 0, stream>>>(cnt, ell, x, dis, Ba, Bb, c1d,
                                                       W3, W4, b3, W34, v1);
    // 4. layer-1 pre-agg (Ba->Bb) + folded c1; extra blocks: W234 + v2
    agg_pre_kernel<<<AGB + C1B + W234XB, 256, 0, stream>>>(Ba, cnt, ell, dis, Bb, c1, c1d,
                                                           W2, b2, W34, W234, v2);
    // 5. fused dense: g = relu(Xa@W1+b1)*dis @ W234 (Bb->Ba)
    gemm_fused_kernel<<<(NN + 15) / 16, 192, 0, stream>>>(Bb, W1, b1, dis, W234, Ba);
    // 6. hop 1 (Ba->Bb) + folded c2
    agg_hop1_kernel<<<AGB + C1B, 256, 0, stream>>>(Ba, cnt, ell, dis, Bb, c1d, c2);
    // 7. hop 2 (Bb->Ba)
    agg_hop2_kernel<<<AGB, 256, 0, stream>>>(Bb, cnt, ell, dis, Ba);
    // 8. hop 3 + rank-1 fixups (Ba->out)
    agg_hop3_kernel<<<AGB, 256, 0, stream>>>(Ba, cnt, ell, dis, c1, c2, v1, v2, b4p, outp);
}